// Round 8
// baseline (544.567 us; speedup 1.0000x reference)
//
#include <hip/hip_runtime.h>

// EdgeNorm, round 12: r10 pipeline + LDS-staged stats reduction.
//
// r11 post-mortem: stats stuck ~123us while occupancy doubled (32->66%) ->
// throughput-bound, not latency. FETCH=124MB (~1.2x payload) so HBM is
// near-minimal; cost is scattered 32B reads + 2 nidx sort passes + 13.6M
// global atomic lane-ops (WRITE 73MB). CBLK 2048 also regressed scatter ->
// revert to r10 (total 429, stats 114).
//
// This round: stats stages its slice payload in LDS (PARTS=16 -> ~1020
// edges = 40KB, coalesced float4 loads), reduction reads LDS (8-lane
// groups read 32B contiguous, <=2-way bank alias = free). nodeacc row
// 17->16 floats = exactly one 64B line (count in separate array) to halve
// atomic dirty lines. 512-thr blocks, 51.7KB LDS -> 3 blocks/CU = 75% occ.
//
// Measured walls (permanent): F1 random 64B-line full pass ~700GB/s;
// F2 17 scattered LDS atomics/edge ~310us. Pipeline dodges both.

#define NHEADS  8
#define KSHIFT  9
#define KNODES  512
#define NNODES  100000
#define NB      196           // ceil(100000/512)
#define CBLK    1024          // count/scatter blocks (r10 proven)
#define CHMAX   3200          // max chunk (local edge idx fits 12 bits)
#define PARTS   16            // stats slices per bucket
#define SLMAX   1280          // max slice len (worst ~1063 at P=1; 32 sigma)

__global__ __launch_bounds__(256)
void count_kernel(const int* __restrict__ dst, unsigned* __restrict__ counts,
                  int p0, int p1, int chunk) {
    __shared__ unsigned hist[NB];
    for (int i = threadIdx.x; i < NB; i += 256) hist[i] = 0u;
    __syncthreads();
    const int blk = blockIdx.x;
    const int s0 = p0 + blk * chunk;
    const int s1 = min(s0 + chunk, p1);
    for (int i = s0 + (int)threadIdx.x * 4; i < s1; i += 256 * 4) {
        if (i + 4 <= s1) {
            int4 d = *reinterpret_cast<const int4*>(dst + i);
            atomicAdd(&hist[(unsigned)d.x >> KSHIFT], 1u);
            atomicAdd(&hist[(unsigned)d.y >> KSHIFT], 1u);
            atomicAdd(&hist[(unsigned)d.z >> KSHIFT], 1u);
            atomicAdd(&hist[(unsigned)d.w >> KSHIFT], 1u);
        } else {
            for (int j = i; j < s1; ++j)
                atomicAdd(&hist[(unsigned)dst[j] >> KSHIFT], 1u);
        }
    }
    __syncthreads();
    for (int b = threadIdx.x; b < NB; b += 256)
        counts[(size_t)b * CBLK + blk] = hist[b];
}

// One block per bucket: exclusive scan of counts[b][0..CBLK) in place.
__global__ __launch_bounds__(256)
void scan_kernel(unsigned* __restrict__ counts, unsigned* __restrict__ totals) {
    __shared__ unsigned sc[256];
    const int b = blockIdx.x;
    const size_t base = (size_t)b * CBLK + (size_t)threadIdx.x * 4;
    uint4 v = *reinterpret_cast<uint4*>(counts + base);
    unsigned s = v.x + v.y + v.z + v.w;
    sc[threadIdx.x] = s;
    __syncthreads();
    for (int off = 1; off < 256; off <<= 1) {
        unsigned t = (threadIdx.x >= (unsigned)off) ? sc[threadIdx.x - off] : 0u;
        __syncthreads();
        sc[threadIdx.x] += t;
        __syncthreads();
    }
    unsigned excl = sc[threadIdx.x] - s;
    uint4 o;
    o.x = excl;
    o.y = excl + v.x;
    o.z = o.y + v.y;
    o.w = o.z + v.z;
    *reinterpret_cast<uint4*>(counts + base) = o;
    if (threadIdx.x == 255) totals[b] = sc[255];
}

// Single block: exclusive prefix over bucket totals -> compact bucket bases.
__global__ __launch_bounds__(256)
void base_kernel(const unsigned* __restrict__ totals, unsigned* __restrict__ base) {
    __shared__ unsigned sc[256];
    unsigned v = (threadIdx.x < NB) ? totals[threadIdx.x] : 0u;
    sc[threadIdx.x] = v;
    __syncthreads();
    for (int off = 1; off < 256; off <<= 1) {
        unsigned t = (threadIdx.x >= (unsigned)off) ? sc[threadIdx.x - off] : 0u;
        __syncthreads();
        sc[threadIdx.x] += t;
        __syncthreads();
    }
    if (threadIdx.x < NB) base[threadIdx.x] = sc[threadIdx.x] - v;
}

// Local counting sort of the chunk by bucket, then coalesced payload emit.
// ord[] entry: local edge idx (12b) | node-in-bucket (9b, <<12) | bucket (<<21)
__global__ __launch_bounds__(256)
void scatter_kernel(const int* __restrict__ dst,
                    const unsigned* __restrict__ counts,
                    const unsigned* __restrict__ base,
                    const float* __restrict__ scores,
                    float* __restrict__ payload,
                    unsigned short* __restrict__ nidx,
                    int p0, int p1, int chunk, unsigned capE) {
    __shared__ unsigned hist[256];      // padded to 256 for the scan
    __shared__ unsigned pfx[NB];        // local exclusive prefix
    __shared__ unsigned lofs[NB];       // running local offsets
    __shared__ unsigned gbase[NB];      // global dest base for this block's run
    __shared__ unsigned ord[CHMAX];
    const int blk = blockIdx.x;
    const int s0 = p0 + blk * chunk;
    const int s1 = min(s0 + chunk, p1);
    const int n  = s1 - s0;

    hist[threadIdx.x] = 0u;
    __syncthreads();
    // phase 1: local histogram
    for (int i = s0 + (int)threadIdx.x * 4; i < s1; i += 256 * 4) {
        if (i + 4 <= s1) {
            int4 d = *reinterpret_cast<const int4*>(dst + i);
            atomicAdd(&hist[(unsigned)d.x >> KSHIFT], 1u);
            atomicAdd(&hist[(unsigned)d.y >> KSHIFT], 1u);
            atomicAdd(&hist[(unsigned)d.z >> KSHIFT], 1u);
            atomicAdd(&hist[(unsigned)d.w >> KSHIFT], 1u);
        } else {
            for (int j = i; j < s1; ++j)
                atomicAdd(&hist[(unsigned)dst[j] >> KSHIFT], 1u);
        }
    }
    __syncthreads();
    // phase 2: in-place inclusive scan of hist -> exclusive pfx
    unsigned myc = hist[threadIdx.x];
    for (int off = 1; off < 256; off <<= 1) {
        unsigned t = (threadIdx.x >= (unsigned)off) ? hist[threadIdx.x - off] : 0u;
        __syncthreads();
        hist[threadIdx.x] += t;
        __syncthreads();
    }
    unsigned excl = hist[threadIdx.x] - myc;
    if (threadIdx.x < NB) {
        pfx[threadIdx.x]  = excl;
        lofs[threadIdx.x] = excl;
        gbase[threadIdx.x] =
            base[threadIdx.x] + counts[(size_t)threadIdx.x * CBLK + blk];
    }
    __syncthreads();
    // phase 3: bucket-order the chunk's edge ids in LDS
    for (int i = s0 + (int)threadIdx.x; i < s1; i += 256) {
        int d = dst[i];
        unsigned b = (unsigned)d >> KSHIFT;
        unsigned pos = atomicAdd(&lofs[b], 1u);
        if (pos < (unsigned)CHMAX)          // invariant: pos < n <= CHMAX
            ord[pos] = (unsigned)(i - s0) |
                       ((unsigned)(d & (KNODES - 1)) << 12) | (b << 21);
    }
    __syncthreads();
    // phase 4: emit payload in bucket order -> contiguous runs.
    // scores gather is a permutation within the chunk's 100KB window (L2-hot).
    for (int p = (int)threadIdx.x; p < n; p += 256) {
        unsigned r = ord[p];
        int el       = (int)(r & 0xFFFu);
        unsigned nib = (r >> 12) & 0x1FFu;
        unsigned b   = r >> 21;
        unsigned gi  = gbase[b] + (unsigned)p - pfx[b];
        if (gi >= capE) continue;           // invariant: gi < pass edge count
        const float4* ps = reinterpret_cast<const float4*>(
            scores + (size_t)(s0 + el) * NHEADS);
        float4 x0 = ps[0], x1 = ps[1];
        float4* pd = reinterpret_cast<float4*>(payload + (size_t)gi * NHEADS);
        pd[0] = x0;
        pd[1] = x1;
        nidx[gi] = (unsigned short)nib;
    }
}

// Block (part,bucket), 512 threads: stage slice payload in LDS (coalesced),
// LDS counting-sort of slice nidx indices, then wave-per-node register
// reduction reading LDS; one wave-wide atomic line per (node,part).
__global__ __launch_bounds__(512)
void stats_kernel(const float* __restrict__ payload,
                  const unsigned short* __restrict__ nidx,
                  const unsigned* __restrict__ totals,
                  const unsigned* __restrict__ baseb,
                  float* __restrict__ nodeacc,
                  float* __restrict__ nodecnt) {
    __shared__ float pay[SLMAX * NHEADS];     // 40.0 KB
    __shared__ unsigned hist[KNODES];         //  2.0 KB
    __shared__ unsigned seg[KNODES + 1];      //  2.0 KB
    __shared__ unsigned cur[KNODES];          //  2.0 KB
    __shared__ unsigned sc[512];              //  2.0 KB
    __shared__ unsigned short sidx[SLMAX];    //  2.5 KB   -> ~51.7 KB total

    const int part  = blockIdx.x;
    const int b     = blockIdx.y;
    const int total = (int)totals[b];
    const int rs    = (int)baseb[b];
    const int sliceLen = (total + PARTS - 1) / PARTS;
    const int l0 = min(total, part * sliceLen);
    const int l1 = min(total, l0 + sliceLen);
    int n = l1 - l0;                        // uniform across block
    if (n <= 0) return;
    if (n > SLMAX) n = SLMAX;               // statistically unreachable guard
    const int gs0 = rs + l0;                // global slice start

    const int tid = (int)threadIdx.x;
    // stage payload slice into LDS, fully coalesced (2 float4 per edge)
    {
        const float4* gp = reinterpret_cast<const float4*>(
            payload + (size_t)gs0 * NHEADS);
        float4* lp = reinterpret_cast<float4*>(pay);
        const int nv = n * 2;
        for (int i = tid; i < nv; i += 512) lp[i] = gp[i];
    }
    if (tid < KNODES) hist[tid] = 0u;
    __syncthreads();
    // pass A: histogram of node-in-bucket over the slice
    for (int i = tid; i < n; i += 512) {
        unsigned k = (unsigned)nidx[gs0 + i] & (KNODES - 1);
        atomicAdd(&hist[k], 1u);
    }
    __syncthreads();
    // exclusive scan of hist[512] with 512 threads
    unsigned v = hist[tid];
    sc[tid] = v;
    __syncthreads();
    for (int off = 1; off < 512; off <<= 1) {
        unsigned t = (tid >= off) ? sc[tid - off] : 0u;
        __syncthreads();
        sc[tid] += t;
        __syncthreads();
    }
    unsigned excl = sc[tid] - v;
    seg[tid] = excl;
    cur[tid] = excl;
    if (tid == 511) seg[KNODES] = sc[511];
    __syncthreads();
    // pass B: place slice-local indices in node-sorted order
    for (int i = tid; i < n; i += 512) {
        unsigned k = (unsigned)nidx[gs0 + i] & (KNODES - 1);
        unsigned pos = atomicAdd(&cur[k], 1u);
        if (pos < (unsigned)SLMAX) sidx[pos] = (unsigned short)i;
    }
    __syncthreads();

    // wave-per-node register reduction, reading LDS (8 waves x 64 nodes)
    const int wv   = tid >> 6;
    const int lane = tid & 63;
    const int grp  = lane >> 3;             // edge slot 0..7
    const int h    = lane & 7;              // head
    for (int k = wv; k < KNODES; k += 8) {
        int ss = (int)seg[k];
        int ee = (int)seg[k + 1];
        int cc = ee - ss;
        if (cc <= 0) continue;
        float sv = 0.f, sw = 0.f;
        for (int j = grp; j < cc; j += 8) {
            int li = (int)sidx[ss + j];
            float x = pay[li * NHEADS + h];
            sv += x;
            sw = fmaf(x, x, sw);
        }
        sv += __shfl_xor(sv, 8);  sw += __shfl_xor(sw, 8);
        sv += __shfl_xor(sv, 16); sw += __shfl_xor(sw, 16);
        sv += __shfl_xor(sv, 32); sw += __shfl_xor(sw, 32);
        int gnode = b * KNODES + k;
        if (gnode < NNODES) {
            if (lane < 16)                      // one 64B line per node
                atomicAdd(&nodeacc[(size_t)gnode * 16 + lane],
                          (lane < 8) ? sv : sw);
            else if (lane == 16)
                atomicAdd(&nodecnt[gnode], (float)cc);
        }
    }
}

// AB layout: per node 16 floats = one 64B line: [A(8) | B(8)].
__global__ __launch_bounds__(256)
void coeff_kernel(const float* __restrict__ nodeacc,
                  const float* __restrict__ nodecnt,
                  const float* __restrict__ gain,
                  const float* __restrict__ bias,
                  float* __restrict__ AB, int total) {
    int i = blockIdx.x * 256 + threadIdx.x;
    if (i >= total) return;
    int node = i >> 3, h = i & 7;
    const float* acc = nodeacc + (size_t)node * 16;
    float s = acc[h];
    float q = acc[8 + h];
    float c = nodecnt[node];
    float cm   = fmaxf(c, 1.0f);                 // ref: sums / max(counts,1)
    float mean = s / cm;
    float var  = fmaxf(q - s * mean, 0.0f);      // one-pass variance, clamped
    float inv  = 1.0f / fmaxf(sqrtf(var / cm), 1e-5f);
    float a = gain[h] * inv;
    AB[(size_t)node * 16 + h]     = a;
    AB[(size_t)node * 16 + 8 + h] = fmaf(-a, mean, bias[h]);
}

__global__ __launch_bounds__(256)
void edge_out_kernel(const float* __restrict__ scores,
                     const int* __restrict__ dst,
                     const float* __restrict__ AB,
                     float* __restrict__ out,
                     int num_edges) {
    int e = blockIdx.x * 256 + threadIdx.x;
    if (e >= num_edges) return;
    int d = dst[e];
    const float4* px  = reinterpret_cast<const float4*>(scores + (size_t)e * NHEADS);
    const float4* pab = reinterpret_cast<const float4*>(AB + (size_t)d * 16);
    float4 x0 = px[0], x1 = px[1];
    float4 a0 = pab[0], a1 = pab[1];
    float4 b0 = pab[2], b1 = pab[3];
    float4 o0, o1;
    o0.x = fmaf(a0.x, x0.x, b0.x);
    o0.y = fmaf(a0.y, x0.y, b0.y);
    o0.z = fmaf(a0.z, x0.z, b0.z);
    o0.w = fmaf(a0.w, x0.w, b0.w);
    o1.x = fmaf(a1.x, x1.x, b1.x);
    o1.y = fmaf(a1.y, x1.y, b1.y);
    o1.z = fmaf(a1.z, x1.z, b1.z);
    o1.w = fmaf(a1.w, x1.w, b1.w);
    float4* po = reinterpret_cast<float4*>(out + (size_t)e * NHEADS);
    po[0] = o0;
    po[1] = o1;
}

// ---- global-atomic fallback (only if ws implausibly small) ----------------
__global__ void edge_stats_fallback(const float* __restrict__ scores,
                                    const int* __restrict__ dst,
                                    float* __restrict__ sums,
                                    float* __restrict__ sumsq,
                                    int* __restrict__ counts,
                                    int num_edges) {
    int e = blockIdx.x * blockDim.x + threadIdx.x;
    if (e >= num_edges) return;
    int d = dst[e];
    const float4* p = reinterpret_cast<const float4*>(scores + (size_t)e * NHEADS);
    float4 x0 = p[0], x1 = p[1];
    float* s = sums  + (size_t)d * NHEADS;
    float* q = sumsq + (size_t)d * NHEADS;
    atomicAdd(s + 0, x0.x); atomicAdd(s + 1, x0.y);
    atomicAdd(s + 2, x0.z); atomicAdd(s + 3, x0.w);
    atomicAdd(s + 4, x1.x); atomicAdd(s + 5, x1.y);
    atomicAdd(s + 6, x1.z); atomicAdd(s + 7, x1.w);
    atomicAdd(q + 0, x0.x * x0.x); atomicAdd(q + 1, x0.y * x0.y);
    atomicAdd(q + 2, x0.z * x0.z); atomicAdd(q + 3, x0.w * x0.w);
    atomicAdd(q + 4, x1.x * x1.x); atomicAdd(q + 5, x1.y * x1.y);
    atomicAdd(q + 6, x1.z * x1.z); atomicAdd(q + 7, x1.w * x1.w);
    atomicAdd(counts + d, 1);
}

__global__ void coeff_fallback(const float* __restrict__ sums,
                               const float* __restrict__ sumsq,
                               const int* __restrict__ counts,
                               const float* __restrict__ gain,
                               const float* __restrict__ bias,
                               float* __restrict__ AB, int total) {
    int i = blockIdx.x * blockDim.x + threadIdx.x;
    if (i >= total) return;
    int h = i & (NHEADS - 1);
    int node = i >> 3;
    float cm = fmaxf((float)counts[node], 1.0f);
    float s = sums[i];
    float mean = s / cm;
    float var_sum = fmaxf(sumsq[i] - s * mean, 0.0f);
    float inv = 1.0f / fmaxf(sqrtf(var_sum / cm), 1e-5f);
    float a = gain[h] * inv;
    AB[(size_t)node * 16 + h]     = a;
    AB[(size_t)node * 16 + 8 + h] = fmaf(-a, mean, bias[h]);
}
// ---------------------------------------------------------------------------

extern "C" void kernel_launch(void* const* d_in, const int* in_sizes, int n_in,
                              void* d_out, int out_size, void* d_ws, size_t ws_size,
                              hipStream_t stream) {
    const float* scores = (const float*)d_in[0];
    const float* gain   = (const float*)d_in[1];
    const float* bias   = (const float*)d_in[2];
    const int*   dst    = (const int*)d_in[3];

    const int E  = in_sizes[3];
    const int N  = NNODES;
    const int NH = N * NHEADS;
    const int B  = 256;

    // Fixed ws sections (256B-aligned):
    //   AB       : N*16 f32          6.40 MB
    //   counts   : NB*CBLK u32       0.80 MB
    //   totals   : NB u32   base : NB u32
    //   nodeacc  : N*16 f32          6.40 MB
    //   nodecnt  : N f32             0.40 MB
    // Per-pass (P=1): payload 102.50 MB, nidx 6.41 MB.
    // Total P=1 ~= 122.9 MB (< 123.7 MB floor proven by r11 running P=1).
    size_t off = 0;
    float* AB = (float*)d_ws;                          off += (size_t)N * 16 * 4;
    off = (off + 255) & ~(size_t)255;
    unsigned* counts = (unsigned*)((char*)d_ws + off); off += (size_t)NB * CBLK * 4;
    off = (off + 255) & ~(size_t)255;
    unsigned* totals = (unsigned*)((char*)d_ws + off); off += (size_t)NB * 4;
    off = (off + 255) & ~(size_t)255;
    unsigned* baseb  = (unsigned*)((char*)d_ws + off); off += (size_t)NB * 4;
    off = (off + 255) & ~(size_t)255;
    float* nodeacc   = (float*)((char*)d_ws + off);    off += (size_t)N * 16 * 4;
    off = (off + 255) & ~(size_t)255;
    float* nodecnt   = (float*)((char*)d_ws + off);    off += (size_t)N * 4;
    off = (off + 255) & ~(size_t)255;
    const size_t fixed = off;

    // Choose pass count: smallest P with chunk<=CHMAX and ws fit.
    int P = 0, chunk = 0;
    size_t payOff = 0, nixOff = 0;
    size_t passCap = 0;
    const int cand[4] = {1, 2, 4, 8};
    for (int ci = 0; ci < 4; ++ci) {
        int p = cand[ci];
        long long perPass = ((long long)E + p - 1) / p;
        long long ch = (((perPass + CBLK - 1) / CBLK) + 3) & ~3LL;
        if (ch > CHMAX) continue;
        size_t passE = (size_t)ch * CBLK;
        size_t po = fixed;
        size_t no = (po + passE * NHEADS * 4 + 255) & ~(size_t)255;
        size_t need = no + passE * 2;
        if (need <= ws_size) {
            P = p; chunk = (int)ch; payOff = po; nixOff = no; passCap = passE;
            break;
        }
    }

    if (P) {
        float* payload = (float*)((char*)d_ws + payOff);
        unsigned short* nidx = (unsigned short*)((char*)d_ws + nixOff);
        hipMemsetAsync(nodeacc, 0, (size_t)N * 16 * 4, stream);
        hipMemsetAsync(nodecnt, 0, (size_t)N * 4, stream);
        for (int pass = 0; pass < P; ++pass) {
            int p0 = pass * chunk * CBLK;
            if (p0 >= E) break;
            int p1 = min(E, p0 + chunk * CBLK);
            count_kernel<<<CBLK, B, 0, stream>>>(dst, counts, p0, p1, chunk);
            scan_kernel<<<NB, B, 0, stream>>>(counts, totals);
            base_kernel<<<1, B, 0, stream>>>(totals, baseb);
            scatter_kernel<<<CBLK, B, 0, stream>>>(dst, counts, baseb, scores,
                                                   payload, nidx, p0, p1, chunk,
                                                   (unsigned)passCap);
            dim3 gs(PARTS, NB);
            stats_kernel<<<gs, 512, 0, stream>>>(payload, nidx, totals, baseb,
                                                 nodeacc, nodecnt);
        }
        coeff_kernel<<<(NH + B - 1) / B, B, 0, stream>>>(nodeacc, nodecnt,
                                                         gain, bias, AB, NH);
        edge_out_kernel<<<(E + B - 1) / B, B, 0, stream>>>(scores, dst, AB,
                                                           (float*)d_out, E);
    } else {
        float* sums  = (float*)((char*)d_ws + (size_t)N * 16 * 4);
        float* sumsq = sums + NH;
        int*   cnts  = (int*)(sumsq + NH);
        hipMemsetAsync(sums, 0,
                       (size_t)(2 * NH) * sizeof(float) + (size_t)N * sizeof(int), stream);
        int blocks_e = (E + B - 1) / B;
        edge_stats_fallback<<<blocks_e, B, 0, stream>>>(scores, dst, sums, sumsq, cnts, E);
        coeff_fallback<<<(NH + B - 1) / B, B, 0, stream>>>(sums, sumsq, cnts, gain, bias, AB, NH);
        edge_out_kernel<<<blocks_e, B, 0, stream>>>(scores, dst, AB, (float*)d_out, E);
    }
}

// Round 9
// 458.327 us; speedup vs baseline: 1.1882x; 1.1882x over previous
//
#include <hip/hip_runtime.h>

// EdgeNorm, round 13: r10 pipeline with INVERTED scatter permutation.
//
// r12 post-mortem: LDS-staged stats fixed reads (FETCH 154->53MB) but
// PARTS=16 atomic output = 129MB of L2 line writebacks at 804 GB/s ->
// stats 230us. WRITE scales linearly with PARTS (37/73/129 at 4/8/16).
// Stats reverted to r10 verbatim (114us, best measured).
//
// Scatter (~220us, the largest cost) is F1-bound on its phase-4 gather:
// scores[el] scattered within 100KB windows, 128 live windows/XCD = 12.8MB
// >> 4MB L2 -> random 64B-line HBM reads at ~700 GB/s. This round inverts
// the permutation: phase 3 stores wpos[local_i] = gi|nib<<22 (no ord[]),
// phase 4 walks chunk order -> scores read COALESCED, payload written
// scattered. Unlike r9 (cross-XCD line ping-pong, 15x write amp), every
// 512B bucket-run segment here is written by ONE block temporally
// clustered -> L2 merges -> ~1.1x write amp expected. LDS 16KB.
//
// Measured walls (permanent): F1 random 64B-line pass ~700GB/s;
// F2 17 scattered LDS atomics/edge ~310us.

#define NHEADS  8
#define KSHIFT  9
#define KNODES  512
#define NNODES  100000
#define NB      196           // ceil(100000/512)
#define CBLK    1024          // count/scatter blocks (r10 proven)
#define CHMAX   3200          // max chunk; chunk*CBLK < 2^22 so gi packs in 22b
#define PARTS   4             // stats slices per bucket (r10 proven)
#define SLMAX   6144          // max slice len (r10 proven)
#define ACCW    20            // nodeacc row: 8 sum | 8 sumsq | count | pad

__global__ __launch_bounds__(256)
void count_kernel(const int* __restrict__ dst, unsigned* __restrict__ counts,
                  int p0, int p1, int chunk) {
    __shared__ unsigned hist[NB];
    for (int i = threadIdx.x; i < NB; i += 256) hist[i] = 0u;
    __syncthreads();
    const int blk = blockIdx.x;
    const int s0 = p0 + blk * chunk;
    const int s1 = min(s0 + chunk, p1);
    for (int i = s0 + (int)threadIdx.x * 4; i < s1; i += 256 * 4) {
        if (i + 4 <= s1) {
            int4 d = *reinterpret_cast<const int4*>(dst + i);
            atomicAdd(&hist[(unsigned)d.x >> KSHIFT], 1u);
            atomicAdd(&hist[(unsigned)d.y >> KSHIFT], 1u);
            atomicAdd(&hist[(unsigned)d.z >> KSHIFT], 1u);
            atomicAdd(&hist[(unsigned)d.w >> KSHIFT], 1u);
        } else {
            for (int j = i; j < s1; ++j)
                atomicAdd(&hist[(unsigned)dst[j] >> KSHIFT], 1u);
        }
    }
    __syncthreads();
    for (int b = threadIdx.x; b < NB; b += 256)
        counts[(size_t)b * CBLK + blk] = hist[b];
}

// One block per bucket: exclusive scan of counts[b][0..CBLK) in place.
__global__ __launch_bounds__(256)
void scan_kernel(unsigned* __restrict__ counts, unsigned* __restrict__ totals) {
    __shared__ unsigned sc[256];
    const int b = blockIdx.x;
    const size_t base = (size_t)b * CBLK + (size_t)threadIdx.x * 4;
    uint4 v = *reinterpret_cast<uint4*>(counts + base);
    unsigned s = v.x + v.y + v.z + v.w;
    sc[threadIdx.x] = s;
    __syncthreads();
    for (int off = 1; off < 256; off <<= 1) {
        unsigned t = (threadIdx.x >= (unsigned)off) ? sc[threadIdx.x - off] : 0u;
        __syncthreads();
        sc[threadIdx.x] += t;
        __syncthreads();
    }
    unsigned excl = sc[threadIdx.x] - s;
    uint4 o;
    o.x = excl;
    o.y = excl + v.x;
    o.z = o.y + v.y;
    o.w = o.z + v.z;
    *reinterpret_cast<uint4*>(counts + base) = o;
    if (threadIdx.x == 255) totals[b] = sc[255];
}

// Single block: exclusive prefix over bucket totals -> compact bucket bases.
__global__ __launch_bounds__(256)
void base_kernel(const unsigned* __restrict__ totals, unsigned* __restrict__ base) {
    __shared__ unsigned sc[256];
    unsigned v = (threadIdx.x < NB) ? totals[threadIdx.x] : 0u;
    sc[threadIdx.x] = v;
    __syncthreads();
    for (int off = 1; off < 256; off <<= 1) {
        unsigned t = (threadIdx.x >= (unsigned)off) ? sc[threadIdx.x - off] : 0u;
        __syncthreads();
        sc[threadIdx.x] += t;
        __syncthreads();
    }
    if (threadIdx.x < NB) base[threadIdx.x] = sc[threadIdx.x] - v;
}

// Inverted-permutation scatter: phase 3 claims ranks and records each
// edge's destination; phase 4 walks CHUNK ORDER -> coalesced score reads,
// scattered payload writes (block-private 512B run segments -> L2-merged).
__global__ __launch_bounds__(256)
void scatter_kernel(const int* __restrict__ dst,
                    const unsigned* __restrict__ counts,
                    const unsigned* __restrict__ base,
                    const float* __restrict__ scores,
                    float* __restrict__ payload,
                    unsigned short* __restrict__ nidx,
                    int p0, int p1, int chunk, unsigned capE) {
    __shared__ unsigned hist[256];      // padded to 256 for the scan
    __shared__ unsigned pfx[NB];        // local exclusive prefix
    __shared__ unsigned lofs[NB];       // running local offsets
    __shared__ unsigned gbase[NB];      // global dest base for this block's run
    __shared__ unsigned wpos[CHMAX];    // per-local-edge: gi | nib<<22
    const int blk = blockIdx.x;
    const int s0 = p0 + blk * chunk;
    const int s1 = min(s0 + chunk, p1);
    const int n  = s1 - s0;

    hist[threadIdx.x] = 0u;
    __syncthreads();
    // phase 1: local histogram
    for (int i = s0 + (int)threadIdx.x * 4; i < s1; i += 256 * 4) {
        if (i + 4 <= s1) {
            int4 d = *reinterpret_cast<const int4*>(dst + i);
            atomicAdd(&hist[(unsigned)d.x >> KSHIFT], 1u);
            atomicAdd(&hist[(unsigned)d.y >> KSHIFT], 1u);
            atomicAdd(&hist[(unsigned)d.z >> KSHIFT], 1u);
            atomicAdd(&hist[(unsigned)d.w >> KSHIFT], 1u);
        } else {
            for (int j = i; j < s1; ++j)
                atomicAdd(&hist[(unsigned)dst[j] >> KSHIFT], 1u);
        }
    }
    __syncthreads();
    // phase 2: in-place inclusive scan of hist -> exclusive pfx
    unsigned myc = hist[threadIdx.x];
    for (int off = 1; off < 256; off <<= 1) {
        unsigned t = (threadIdx.x >= (unsigned)off) ? hist[threadIdx.x - off] : 0u;
        __syncthreads();
        hist[threadIdx.x] += t;
        __syncthreads();
    }
    unsigned excl = hist[threadIdx.x] - myc;
    if (threadIdx.x < NB) {
        pfx[threadIdx.x]  = excl;
        lofs[threadIdx.x] = excl;
        gbase[threadIdx.x] =
            base[threadIdx.x] + counts[(size_t)threadIdx.x * CBLK + blk];
    }
    __syncthreads();
    // phase 3: claim rank within (bucket, block) segment -> record dest.
    // gi < capE <= CHMAX*CBLK < 2^22, nib < 512 -> packs in u32.
    for (int i = s0 + (int)threadIdx.x; i < s1; i += 256) {
        int d = dst[i];
        unsigned b   = (unsigned)d >> KSHIFT;
        unsigned pos = atomicAdd(&lofs[b], 1u);
        unsigned gi  = gbase[b] + (pos - pfx[b]);
        unsigned nib = (unsigned)d & (KNODES - 1);
        wpos[i - s0] = (gi < capE) ? (gi | (nib << 22)) : 0xFFFFFFFFu;
    }
    __syncthreads();
    // phase 4: chunk-order walk -> coalesced reads, L2-merged scattered writes
    for (int i = (int)threadIdx.x; i < n; i += 256) {
        unsigned r = wpos[i];
        if (r == 0xFFFFFFFFu) continue;     // guarded-impossible
        unsigned gi  = r & 0x3FFFFFu;
        unsigned nib = r >> 22;
        const float4* ps = reinterpret_cast<const float4*>(
            scores + (size_t)(s0 + i) * NHEADS);
        float4 x0 = ps[0], x1 = ps[1];
        float4* pd = reinterpret_cast<float4*>(payload + (size_t)gi * NHEADS);
        pd[0] = x0;
        pd[1] = x1;
        nidx[gi] = (unsigned short)nib;
    }
}

// Block (part,bucket): LDS counting-sort of the slice's nidx indices, then
// one WAVE per node: 64 lanes = 8 edges x 8 heads, butterfly over edge
// groups, single wave-wide atomicAdd into nodeacc[node][0..16].  (r10)
__global__ __launch_bounds__(256)
void stats_kernel(const float* __restrict__ payload,
                  const unsigned short* __restrict__ nidx,
                  const unsigned* __restrict__ totals,
                  const unsigned* __restrict__ baseb,
                  float* __restrict__ nodeacc) {
    __shared__ unsigned hist[KNODES];
    __shared__ unsigned seg[KNODES + 1];
    __shared__ unsigned cur[KNODES];
    __shared__ unsigned sc[256];
    __shared__ unsigned short sidx[SLMAX];

    const int part  = blockIdx.x;
    const int b     = blockIdx.y;
    const int total = (int)totals[b];
    const int rs    = (int)baseb[b];
    const int sliceLen = (total + PARTS - 1) / PARTS;
    const int l0 = min(total, part * sliceLen);
    const int l1 = min(total, l0 + sliceLen);
    const int n  = l1 - l0;                 // uniform across block
    if (n <= 0) return;
    const int gs0 = rs + l0;                // global slice start

    const int tid = (int)threadIdx.x;
    for (int i = tid; i < KNODES; i += 256) hist[i] = 0u;
    __syncthreads();
    // pass A: histogram of node-in-bucket over the slice
    for (int i = tid; i < n; i += 256) {
        if (i >= SLMAX) break;
        unsigned k = (unsigned)nidx[gs0 + i] & (KNODES - 1);
        atomicAdd(&hist[k], 1u);
    }
    __syncthreads();
    // exclusive scan of hist[512] with 256 threads (pairwise)
    unsigned a0 = hist[2 * tid];
    unsigned a1 = hist[2 * tid + 1];
    unsigned ps = a0 + a1;
    sc[tid] = ps;
    __syncthreads();
    for (int off = 1; off < 256; off <<= 1) {
        unsigned t = (tid >= off) ? sc[tid - off] : 0u;
        __syncthreads();
        sc[tid] += t;
        __syncthreads();
    }
    unsigned pexcl = sc[tid] - ps;
    seg[2 * tid]     = pexcl;
    seg[2 * tid + 1] = pexcl + a0;
    cur[2 * tid]     = pexcl;
    cur[2 * tid + 1] = pexcl + a0;
    if (tid == 255) seg[KNODES] = sc[255];
    __syncthreads();
    // pass B: place slice-local indices in node-sorted order
    for (int i = tid; i < n; i += 256) {
        if (i >= SLMAX) break;
        unsigned k = (unsigned)nidx[gs0 + i] & (KNODES - 1);
        unsigned pos = atomicAdd(&cur[k], 1u);
        if (pos < (unsigned)SLMAX) sidx[pos] = (unsigned short)i;
    }
    __syncthreads();

    // wave-per-node register reduction
    const int wv   = tid >> 6;
    const int lane = tid & 63;
    const int grp  = lane >> 3;             // edge slot 0..7
    const int h    = lane & 7;              // head
    for (int k = wv; k < KNODES; k += 4) {
        int ss = (int)seg[k];
        int ee = (int)seg[k + 1];
        int cc = ee - ss;
        if (cc <= 0) continue;
        float v = 0.f, w = 0.f;
        for (int j = grp; j < cc; j += 8) {
            int li = (int)sidx[ss + j];
            float x = payload[(size_t)(gs0 + li) * NHEADS + h];
            v += x;
            w = fmaf(x, x, w);
        }
        v += __shfl_xor(v, 8);  w += __shfl_xor(w, 8);
        v += __shfl_xor(v, 16); w += __shfl_xor(w, 16);
        v += __shfl_xor(v, 32); w += __shfl_xor(w, 32);
        int gnode = b * KNODES + k;
        if (lane < 17 && gnode < NNODES) {
            float val = (lane < 8) ? v : ((lane < 16) ? w : (float)cc);
            atomicAdd(&nodeacc[(size_t)gnode * ACCW + lane], val);
        }
    }
}

// AB layout: per node 16 floats = one 64B line: [A(8) | B(8)].
__global__ __launch_bounds__(256)
void coeff_kernel(const float* __restrict__ nodeacc,
                  const float* __restrict__ gain,
                  const float* __restrict__ bias,
                  float* __restrict__ AB, int total) {
    int i = blockIdx.x * 256 + threadIdx.x;
    if (i >= total) return;
    int node = i >> 3, h = i & 7;
    const float* acc = nodeacc + (size_t)node * ACCW;
    float s = acc[h];
    float q = acc[8 + h];
    float c = acc[16];
    float cm   = fmaxf(c, 1.0f);                 // ref: sums / max(counts,1)
    float mean = s / cm;
    float var  = fmaxf(q - s * mean, 0.0f);      // one-pass variance, clamped
    float inv  = 1.0f / fmaxf(sqrtf(var / cm), 1e-5f);
    float a = gain[h] * inv;
    AB[(size_t)node * 16 + h]     = a;
    AB[(size_t)node * 16 + 8 + h] = fmaf(-a, mean, bias[h]);
}

__global__ __launch_bounds__(256)
void edge_out_kernel(const float* __restrict__ scores,
                     const int* __restrict__ dst,
                     const float* __restrict__ AB,
                     float* __restrict__ out,
                     int num_edges) {
    int e = blockIdx.x * 256 + threadIdx.x;
    if (e >= num_edges) return;
    int d = dst[e];
    const float4* px  = reinterpret_cast<const float4*>(scores + (size_t)e * NHEADS);
    const float4* pab = reinterpret_cast<const float4*>(AB + (size_t)d * 16);
    float4 x0 = px[0], x1 = px[1];
    float4 a0 = pab[0], a1 = pab[1];
    float4 b0 = pab[2], b1 = pab[3];
    float4 o0, o1;
    o0.x = fmaf(a0.x, x0.x, b0.x);
    o0.y = fmaf(a0.y, x0.y, b0.y);
    o0.z = fmaf(a0.z, x0.z, b0.z);
    o0.w = fmaf(a0.w, x0.w, b0.w);
    o1.x = fmaf(a1.x, x1.x, b1.x);
    o1.y = fmaf(a1.y, x1.y, b1.y);
    o1.z = fmaf(a1.z, x1.z, b1.z);
    o1.w = fmaf(a1.w, x1.w, b1.w);
    float4* po = reinterpret_cast<float4*>(out + (size_t)e * NHEADS);
    po[0] = o0;
    po[1] = o1;
}

// ---- global-atomic fallback (only if ws implausibly small) ----------------
__global__ void edge_stats_fallback(const float* __restrict__ scores,
                                    const int* __restrict__ dst,
                                    float* __restrict__ sums,
                                    float* __restrict__ sumsq,
                                    int* __restrict__ counts,
                                    int num_edges) {
    int e = blockIdx.x * blockDim.x + threadIdx.x;
    if (e >= num_edges) return;
    int d = dst[e];
    const float4* p = reinterpret_cast<const float4*>(scores + (size_t)e * NHEADS);
    float4 x0 = p[0], x1 = p[1];
    float* s = sums  + (size_t)d * NHEADS;
    float* q = sumsq + (size_t)d * NHEADS;
    atomicAdd(s + 0, x0.x); atomicAdd(s + 1, x0.y);
    atomicAdd(s + 2, x0.z); atomicAdd(s + 3, x0.w);
    atomicAdd(s + 4, x1.x); atomicAdd(s + 5, x1.y);
    atomicAdd(s + 6, x1.z); atomicAdd(s + 7, x1.w);
    atomicAdd(q + 0, x0.x * x0.x); atomicAdd(q + 1, x0.y * x0.y);
    atomicAdd(q + 2, x0.z * x0.z); atomicAdd(q + 3, x0.w * x0.w);
    atomicAdd(q + 4, x1.x * x1.x); atomicAdd(q + 5, x1.y * x1.y);
    atomicAdd(q + 6, x1.z * x1.z); atomicAdd(q + 7, x1.w * x1.w);
    atomicAdd(counts + d, 1);
}

__global__ void coeff_fallback(const float* __restrict__ sums,
                               const float* __restrict__ sumsq,
                               const int* __restrict__ counts,
                               const float* __restrict__ gain,
                               const float* __restrict__ bias,
                               float* __restrict__ AB, int total) {
    int i = blockIdx.x * blockDim.x + threadIdx.x;
    if (i >= total) return;
    int h = i & (NHEADS - 1);
    int node = i >> 3;
    float cm = fmaxf((float)counts[node], 1.0f);
    float s = sums[i];
    float mean = s / cm;
    float var_sum = fmaxf(sumsq[i] - s * mean, 0.0f);
    float inv = 1.0f / fmaxf(sqrtf(var_sum / cm), 1e-5f);
    float a = gain[h] * inv;
    AB[(size_t)node * 16 + h]     = a;
    AB[(size_t)node * 16 + 8 + h] = fmaf(-a, mean, bias[h]);
}
// ---------------------------------------------------------------------------

extern "C" void kernel_launch(void* const* d_in, const int* in_sizes, int n_in,
                              void* d_out, int out_size, void* d_ws, size_t ws_size,
                              hipStream_t stream) {
    const float* scores = (const float*)d_in[0];
    const float* gain   = (const float*)d_in[1];
    const float* bias   = (const float*)d_in[2];
    const int*   dst    = (const int*)d_in[3];

    const int E  = in_sizes[3];
    const int N  = NNODES;
    const int NH = N * NHEADS;
    const int B  = 256;

    // Fixed ws sections (256B-aligned), identical to r10 (proven P=1 fit):
    //   AB       : N*16 f32          6.40 MB
    //   counts   : NB*CBLK u32       0.80 MB
    //   totals   : NB u32   base : NB u32
    //   nodeacc  : N*ACCW f32        8.00 MB
    // Per-pass (P=1): payload 102.50 MB, nidx 6.41 MB -> ~124.1 MB total.
    size_t off = 0;
    float* AB = (float*)d_ws;                          off += (size_t)N * 16 * 4;
    off = (off + 255) & ~(size_t)255;
    unsigned* counts = (unsigned*)((char*)d_ws + off); off += (size_t)NB * CBLK * 4;
    off = (off + 255) & ~(size_t)255;
    unsigned* totals = (unsigned*)((char*)d_ws + off); off += (size_t)NB * 4;
    off = (off + 255) & ~(size_t)255;
    unsigned* baseb  = (unsigned*)((char*)d_ws + off); off += (size_t)NB * 4;
    off = (off + 255) & ~(size_t)255;
    float* nodeacc   = (float*)((char*)d_ws + off);    off += (size_t)N * ACCW * 4;
    off = (off + 255) & ~(size_t)255;
    const size_t fixed = off;

    // Choose pass count: smallest P with chunk<=CHMAX and ws fit.
    int P = 0, chunk = 0;
    size_t payOff = 0, nixOff = 0;
    size_t passCap = 0;
    const int cand[4] = {1, 2, 4, 8};
    for (int ci = 0; ci < 4; ++ci) {
        int p = cand[ci];
        long long perPass = ((long long)E + p - 1) / p;
        long long ch = (((perPass + CBLK - 1) / CBLK) + 3) & ~3LL;
        if (ch > CHMAX) continue;
        size_t passE = (size_t)ch * CBLK;
        size_t po = fixed;
        size_t no = (po + passE * NHEADS * 4 + 255) & ~(size_t)255;
        size_t need = no + passE * 2;
        if (need <= ws_size) {
            P = p; chunk = (int)ch; payOff = po; nixOff = no; passCap = passE;
            break;
        }
    }

    if (P) {
        float* payload = (float*)((char*)d_ws + payOff);
        unsigned short* nidx = (unsigned short*)((char*)d_ws + nixOff);
        hipMemsetAsync(nodeacc, 0, (size_t)N * ACCW * 4, stream);
        for (int pass = 0; pass < P; ++pass) {
            int p0 = pass * chunk * CBLK;
            if (p0 >= E) break;
            int p1 = min(E, p0 + chunk * CBLK);
            count_kernel<<<CBLK, B, 0, stream>>>(dst, counts, p0, p1, chunk);
            scan_kernel<<<NB, B, 0, stream>>>(counts, totals);
            base_kernel<<<1, B, 0, stream>>>(totals, baseb);
            scatter_kernel<<<CBLK, B, 0, stream>>>(dst, counts, baseb, scores,
                                                   payload, nidx, p0, p1, chunk,
                                                   (unsigned)passCap);
            dim3 gs(PARTS, NB);
            stats_kernel<<<gs, B, 0, stream>>>(payload, nidx, totals, baseb,
                                               nodeacc);
        }
        coeff_kernel<<<(NH + B - 1) / B, B, 0, stream>>>(nodeacc, gain, bias, AB, NH);
        edge_out_kernel<<<(E + B - 1) / B, B, 0, stream>>>(scores, dst, AB,
                                                           (float*)d_out, E);
    } else {
        float* sums  = (float*)((char*)d_ws + (size_t)N * 16 * 4);
        float* sumsq = sums + NH;
        int*   cnts  = (int*)(sumsq + NH);
        hipMemsetAsync(sums, 0,
                       (size_t)(2 * NH) * sizeof(float) + (size_t)N * sizeof(int), stream);
        int blocks_e = (E + B - 1) / B;
        edge_stats_fallback<<<blocks_e, B, 0, stream>>>(scores, dst, sums, sumsq, cnts, E);
        coeff_fallback<<<(NH + B - 1) / B, B, 0, stream>>>(sums, sumsq, cnts, gain, bias, AB, NH);
        edge_out_kernel<<<blocks_e, B, 0, stream>>>(scores, dst, AB, (float*)d_out, E);
    }
}